// Round 5
// baseline (2627.100 us; speedup 1.0000x reference)
//
#include <hip/hip_runtime.h>
#include <stdint.h>

#define N_HOST 50000
#define N_FLOW 200000
#define DIM 128
#define DOUTN 32
#define NEDGE 1000000
#define NLAYER 2

#define GSH 6                        // 64 dsts per bucket (both directions)
#define NB_F ((N_FLOW + 63) >> 6)    // 3125
#define NB_H ((N_HOST + 63) >> 6)    // 782
#define AST 136                      // bf16 LDS row stride (272B: 2-way banks only)

typedef __bf16 bf16;
typedef __bf16 bf16x4 __attribute__((ext_vector_type(4)));
typedef __bf16 bf16x8 __attribute__((ext_vector_type(8)));
typedef float floatx4 __attribute__((ext_vector_type(4)));

// ---------------- cast f32 -> bf16, 4 elems/thread ----------------
__global__ void cast_f32_bf16_k(const float* __restrict__ in, bf16* __restrict__ out, int n) {
    int i = (blockIdx.x * 256 + threadIdx.x) * 4;
    if (i + 3 < n) {
        float4 v = *(const float4*)(in + i);
        bf16x4 o;
        o[0] = (bf16)v.x; o[1] = (bf16)v.y; o[2] = (bf16)v.z; o[3] = (bf16)v.w;
        *(bf16x4*)(out + i) = o;
    } else {
        for (int j = 0; j < 4 && i + j < n; ++j) out[i + j] = (bf16)in[i + j];
    }
}

// ---------------- weight repack: f32 [128x128] -> bf16 MFMA B-fragment layout ----
__global__ void repack_w_k(const float* __restrict__ W, bf16* __restrict__ out) {
    int mat = blockIdx.y;
    int w = blockIdx.x * 4 + (threadIdx.x >> 6);   // 0..31
    int lane = threadIdx.x & 63;
    int ct = w >> 2, k0q = w & 3;
    int quad = lane >> 4, m = lane & 15;
    const float* Wm = W + (size_t)mat * DIM * DIM;
    bf16* om = out + (size_t)mat * DIM * DIM;
    bf16x8 o;
#pragma unroll
    for (int j = 0; j < 8; ++j) o[j] = (bf16)Wm[(k0q * 32 + quad * 8 + j) * DIM + ct * 16 + m];
    *(bf16x8*)(om + ((ct * 4 + k0q) * 64 + lane) * 8) = o;
}

__global__ void repack_wout_k(const float* __restrict__ W, bf16* __restrict__ out) {
    int w = blockIdx.x * 4 + (threadIdx.x >> 6);   // 0..7
    int lane = threadIdx.x & 63;
    int ct = w >> 2, k0q = w & 3;
    int quad = lane >> 4, m = lane & 15;
    bf16x8 o;
#pragma unroll
    for (int j = 0; j < 8; ++j) o[j] = (bf16)W[(k0q * 32 + quad * 8 + j) * DOUTN + ct * 16 + m];
    *(bf16x8*)(out + ((ct * 4 + k0q) * 64 + lane) * 8) = o;
}

// ---------------- bucketed edge partition (no per-dst sort needed) ----------------
__global__ __launch_bounds__(256)
void bucket_count_k(const int* __restrict__ dst, int* __restrict__ bcount, int n, int nb) {
    __shared__ int lc[3200];
    int t = threadIdx.x;
    for (int i = t; i < nb; i += 256) lc[i] = 0;
    __syncthreads();
    int base = blockIdx.x * 8192;
    int end = base + 8192; if (end > n) end = n;
    for (int i = base + t; i < end; i += 256)
        atomicAdd(&lc[dst[i] >> GSH], 1);
    __syncthreads();
    for (int i = t; i < nb; i += 256) {
        int v = lc[i];
        if (v) atomicAdd(&bcount[i], v);
    }
}

// single-block scan over nb (chunked by 1024), emits boffs + padded cursors
__global__ __launch_bounds__(256)
void bucket_scan_k(const int* __restrict__ bcount, int* __restrict__ boffs,
                   int* __restrict__ bcur, int nb) {
    __shared__ int sd[256];
    int t = threadIdx.x;
    int carry = 0;
    for (int c0 = 0; c0 < nb; c0 += 1024) {
        int v[4]; int ts = 0;
#pragma unroll
        for (int j = 0; j < 4; ++j) {
            int i = c0 + t * 4 + j;
            v[j] = (i < nb) ? bcount[i] : 0; ts += v[j];
        }
        int x = ts;
        sd[t] = x; __syncthreads();
        for (int o = 1; o < 256; o <<= 1) {
            int y = (t >= o) ? sd[t - o] : 0;
            __syncthreads();
            x += y; sd[t] = x; __syncthreads();
        }
        int run = x - ts + carry;
#pragma unroll
        for (int j = 0; j < 4; ++j) {
            int i = c0 + t * 4 + j;
            if (i < nb) { boffs[i] = run; bcur[i << 4] = run; }
            run += v[j];
        }
        carry += sd[255];
        __syncthreads();
    }
    if (t == 0) boffs[nb] = carry;
}

__global__ __launch_bounds__(256)
void bucket_scatter_k(const int* __restrict__ src, const int* __restrict__ dst,
                      int* bcur, int* __restrict__ bkey, int n) {
    int e = blockIdx.x * 256 + threadIdx.x;
    if (e < n) {
        int d = dst[e];
        int b = d >> GSH;
        int p = atomicAdd(&bcur[b << 4], 1);
        bkey[p] = (src[e] << 8) | (d & 63);
    }
}

// ---------------- fused SAGE layer: bucket of 64 dst rows per block ----------------
// phase 1: edge-parallel gather of raw source rows into 64x128 f32 LDS (ds_add_f32,
//          +dl*4 column swizzle to spread bank cosets); degrees counted in LDS.
// convert: mean -> bf16 A-layout tile (stride AST).
// phase 2: MFMA mean@Wl + Xd@Wr, + biases, leaky_relu, store bf16.
__global__ __launch_bounds__(256)
void fused_sage_dual(const int* __restrict__ boffs, const int* __restrict__ bkey,
                     const bf16x8* __restrict__ Xs8, const bf16* __restrict__ Xd,
                     const bf16* __restrict__ Wlf, const bf16* __restrict__ Wrf,
                     const float* __restrict__ b1, const float* __restrict__ b2,
                     bf16* __restrict__ out, int n_dst) {
    __shared__ __align__(16) float lacc[64 * DIM];    // 32 KB
    __shared__ float ldeg[64];
    __shared__ __align__(16) bf16 lmb[64 * AST];      // 17.4 KB
    int t = threadIdx.x;
    int row0 = blockIdx.x << 6;
    for (int i = t; i < 64 * DIM; i += 256) lacc[i] = 0.f;
    if (t < 64) ldeg[t] = 0.f;
    __syncthreads();

    int e0 = boffs[blockIdx.x], e1 = boffs[blockIdx.x + 1];
    {
        int slot = t >> 4, mm = t & 15;
        for (int e = e0 + slot; e < e1; e += 16) {
            int key = bkey[e];
            int src = key >> 8, dl = key & 63;
            bf16x8 v = Xs8[src * 16 + mm];
            if (mm == 0) atomicAdd(&ldeg[dl], 1.0f);
            int cb = mm * 8 + dl * 4;
#pragma unroll
            for (int j = 0; j < 8; ++j)
                atomicAdd(&lacc[dl * DIM + ((cb + j) & 127)], (float)v[j]);
        }
    }
    __syncthreads();
    {
        int row = t >> 2, cseg = (t & 3) * 32;
        float d = ldeg[row];
        float inv = d > 0.f ? 1.0f / d : 0.f;
        for (int c = cseg; c < cseg + 32; ++c)
            lmb[row * AST + c] = (bf16)(lacc[row * DIM + ((c + row * 4) & 127)] * inv);
    }
    __syncthreads();

    int lane = t & 63, wv = t >> 6;
    int quad = lane >> 4, m = lane & 15;
    bf16x8 BL[2][4], BR[2][4];
#pragma unroll
    for (int tt = 0; tt < 2; ++tt) {
        int ct = wv * 2 + tt;
#pragma unroll
        for (int k = 0; k < 4; ++k) {
            BL[tt][k] = *(const bf16x8*)(Wlf + ((ct * 4 + k) * 64 + lane) * 8);
            BR[tt][k] = *(const bf16x8*)(Wrf + ((ct * 4 + k) * 64 + lane) * 8);
        }
    }
    int c0 = wv * 32 + m, c1 = wv * 32 + 16 + m;
    float bias0 = b1[c0] + b2[c0], bias1 = b1[c1] + b2[c1];
#pragma unroll
    for (int tm = 0; tm < 4; ++tm) {
        floatx4 a0 = {0.f, 0.f, 0.f, 0.f}, a1 = {0.f, 0.f, 0.f, 0.f};
        const bf16* lp = lmb + (tm * 16 + m) * AST + quad * 8;
        int grow = row0 + tm * 16 + m; if (grow >= n_dst) grow = n_dst - 1;
        const bf16* gp = Xd + grow * DIM + quad * 8;
#pragma unroll
        for (int k = 0; k < 4; ++k) {
            bf16x8 am = *(const bf16x8*)(lp + k * 32);
            a0 = __builtin_amdgcn_mfma_f32_16x16x32_bf16(am, BL[0][k], a0, 0, 0, 0);
            a1 = __builtin_amdgcn_mfma_f32_16x16x32_bf16(am, BL[1][k], a1, 0, 0, 0);
        }
#pragma unroll
        for (int k = 0; k < 4; ++k) {
            bf16x8 ax = *(const bf16x8*)(gp + k * 32);
            a0 = __builtin_amdgcn_mfma_f32_16x16x32_bf16(ax, BR[0][k], a0, 0, 0, 0);
            a1 = __builtin_amdgcn_mfma_f32_16x16x32_bf16(ax, BR[1][k], a1, 0, 0, 0);
        }
#pragma unroll
        for (int r = 0; r < 4; ++r) {
            int row = row0 + tm * 16 + quad * 4 + r;
            if (row < n_dst) {
                float v0 = a0[r] + bias0; v0 = v0 > 0.f ? v0 : 0.01f * v0;
                float v1 = a1[r] + bias1; v1 = v1 > 0.f ? v1 : 0.01f * v1;
                out[row * DIM + c0] = (bf16)v0;
                out[row * DIM + c1] = (bf16)v1;
            }
        }
    }
}

// ---------------- layer-1 flow variant: + fused @W_out, f32 output, f2 never in HBM ----
// (flow only: n_dst = 200000 = 3125*64 exactly, no row guards needed)
__global__ __launch_bounds__(256)
void fused_sage_dual_out(const int* __restrict__ boffs, const int* __restrict__ bkey,
                         const bf16x8* __restrict__ Xs8, const bf16* __restrict__ Xd,
                         const bf16* __restrict__ Wlf, const bf16* __restrict__ Wrf,
                         const float* __restrict__ b1, const float* __restrict__ b2,
                         const bf16* __restrict__ Wof, const float* __restrict__ bo,
                         float* __restrict__ outf) {
    __shared__ __align__(16) float lacc[64 * DIM];    // reused as f2 (bf16) after convert
    __shared__ float ldeg[64];
    __shared__ __align__(16) bf16 lmb[64 * AST];
    bf16* f2 = (bf16*)lacc;
    int t = threadIdx.x;
    int row0 = blockIdx.x << 6;
    for (int i = t; i < 64 * DIM; i += 256) lacc[i] = 0.f;
    if (t < 64) ldeg[t] = 0.f;
    __syncthreads();

    int e0 = boffs[blockIdx.x], e1 = boffs[blockIdx.x + 1];
    {
        int slot = t >> 4, mm = t & 15;
        for (int e = e0 + slot; e < e1; e += 16) {
            int key = bkey[e];
            int src = key >> 8, dl = key & 63;
            bf16x8 v = Xs8[src * 16 + mm];
            if (mm == 0) atomicAdd(&ldeg[dl], 1.0f);
            int cb = mm * 8 + dl * 4;
#pragma unroll
            for (int j = 0; j < 8; ++j)
                atomicAdd(&lacc[dl * DIM + ((cb + j) & 127)], (float)v[j]);
        }
    }
    __syncthreads();
    {
        int row = t >> 2, cseg = (t & 3) * 32;
        float d = ldeg[row];
        float inv = d > 0.f ? 1.0f / d : 0.f;
        for (int c = cseg; c < cseg + 32; ++c)
            lmb[row * AST + c] = (bf16)(lacc[row * DIM + ((c + row * 4) & 127)] * inv);
    }
    __syncthreads();   // lacc (f32 means) fully consumed into lmb; safe to reuse as f2

    int lane = t & 63, wv = t >> 6;
    int quad = lane >> 4, m = lane & 15;
    bf16x8 BL[2][4], BR[2][4];
#pragma unroll
    for (int tt = 0; tt < 2; ++tt) {
        int ct = wv * 2 + tt;
#pragma unroll
        for (int k = 0; k < 4; ++k) {
            BL[tt][k] = *(const bf16x8*)(Wlf + ((ct * 4 + k) * 64 + lane) * 8);
            BR[tt][k] = *(const bf16x8*)(Wrf + ((ct * 4 + k) * 64 + lane) * 8);
        }
    }
    int c0 = wv * 32 + m, c1 = wv * 32 + 16 + m;
    float bias0 = b1[c0] + b2[c0], bias1 = b1[c1] + b2[c1];
#pragma unroll
    for (int tm = 0; tm < 4; ++tm) {
        floatx4 a0 = {0.f, 0.f, 0.f, 0.f}, a1 = {0.f, 0.f, 0.f, 0.f};
        const bf16* lp = lmb + (tm * 16 + m) * AST + quad * 8;
        const bf16* gp = Xd + (row0 + tm * 16 + m) * DIM + quad * 8;
#pragma unroll
        for (int k = 0; k < 4; ++k) {
            bf16x8 am = *(const bf16x8*)(lp + k * 32);
            a0 = __builtin_amdgcn_mfma_f32_16x16x32_bf16(am, BL[0][k], a0, 0, 0, 0);
            a1 = __builtin_amdgcn_mfma_f32_16x16x32_bf16(am, BL[1][k], a1, 0, 0, 0);
        }
#pragma unroll
        for (int k = 0; k < 4; ++k) {
            bf16x8 ax = *(const bf16x8*)(gp + k * 32);
            a0 = __builtin_amdgcn_mfma_f32_16x16x32_bf16(ax, BR[0][k], a0, 0, 0, 0);
            a1 = __builtin_amdgcn_mfma_f32_16x16x32_bf16(ax, BR[1][k], a1, 0, 0, 0);
        }
#pragma unroll
        for (int r = 0; r < 4; ++r) {
            int lr = tm * 16 + quad * 4 + r;
            float v0 = a0[r] + bias0; v0 = v0 > 0.f ? v0 : 0.01f * v0;
            float v1 = a1[r] + bias1; v1 = v1 > 0.f ? v1 : 0.01f * v1;
            f2[lr * AST + c0] = (bf16)v0;
            f2[lr * AST + c1] = (bf16)v1;
        }
    }
    __syncthreads();
    // W_out stage: wave wv handles row-tile wv (16 rows) x 32 out-cols
    bf16x8 BO[2][4];
#pragma unroll
    for (int ct = 0; ct < 2; ++ct)
#pragma unroll
        for (int k = 0; k < 4; ++k)
            BO[ct][k] = *(const bf16x8*)(Wof + ((ct * 4 + k) * 64 + lane) * 8);
    floatx4 o0 = {0.f, 0.f, 0.f, 0.f}, o1 = {0.f, 0.f, 0.f, 0.f};
    const bf16* fp = f2 + (wv * 16 + m) * AST + quad * 8;
#pragma unroll
    for (int k = 0; k < 4; ++k) {
        bf16x8 af = *(const bf16x8*)(fp + k * 32);
        o0 = __builtin_amdgcn_mfma_f32_16x16x32_bf16(af, BO[0][k], o0, 0, 0, 0);
        o1 = __builtin_amdgcn_mfma_f32_16x16x32_bf16(af, BO[1][k], o1, 0, 0, 0);
    }
    float bo0 = bo[m], bo1 = bo[16 + m];
#pragma unroll
    for (int r = 0; r < 4; ++r) {
        int row = row0 + wv * 16 + quad * 4 + r;
        outf[row * DOUTN + m] = o0[r] + bo0;
        outf[row * DOUTN + 16 + m] = o1[r] + bo1;
    }
}

extern "C" void kernel_launch(void* const* d_in, const int* in_sizes, int n_in,
                              void* d_out, int out_size, void* d_ws, size_t ws_size,
                              hipStream_t stream) {
    (void)in_sizes; (void)n_in; (void)out_size; (void)ws_size;
    const float* x_host  = (const float*)d_in[0];
    const float* x_flow  = (const float*)d_in[1];
    const int*   ehf_src = (const int*)d_in[2];
    const int*   ehf_dst = (const int*)d_in[3];
    const int*   efh_src = (const int*)d_in[4];
    const int*   efh_dst = (const int*)d_in[5];
    const float* Wl      = (const float*)d_in[6];
    const float* bl      = (const float*)d_in[7];
    const float* Wr      = (const float*)d_in[8];
    const float* br      = (const float*)d_in[9];
    const float* W_out   = (const float*)d_in[10];
    const float* b_out   = (const float*)d_in[11];
    float* out = (float*)d_out;

    char* basep = (char*)d_ws;
    size_t off = 0;
    auto alloc = [&](size_t b) -> void* {
        void* p = basep + off;
        off += (b + 255) & ~(size_t)255;
        return p;
    };

    bf16* fA  = (bf16*)alloc((size_t)N_FLOW * DIM * 2);
    bf16* fB  = (bf16*)alloc((size_t)N_FLOW * DIM * 2);
    bf16* hA  = (bf16*)alloc((size_t)N_HOST * DIM * 2);
    bf16* hB  = (bf16*)alloc((size_t)N_HOST * DIM * 2);
    bf16* WlF = (bf16*)alloc((size_t)NLAYER * 2 * DIM * DIM * 2);
    bf16* WrF = (bf16*)alloc((size_t)NLAYER * 2 * DIM * DIM * 2);
    bf16* WoF = (bf16*)alloc((size_t)DIM * DOUTN * 2);

    int* bcountF = (int*)alloc((size_t)NB_F * 4);
    int* boffsF  = (int*)alloc((size_t)(NB_F + 1) * 4);
    int* bcurF   = (int*)alloc((size_t)NB_F * 16 * 4);
    int* bkeyF   = (int*)alloc((size_t)NEDGE * 4);
    int* bcountH = (int*)alloc((size_t)NB_H * 4);
    int* boffsH  = (int*)alloc((size_t)(NB_H + 1) * 4);
    int* bcurH   = (int*)alloc((size_t)NB_H * 16 * 4);
    int* bkeyH   = (int*)alloc((size_t)NEDGE * 4);

    // casts + weight repacks
    {
        int n = N_FLOW * DIM;
        cast_f32_bf16_k<<<(n / 4 + 255) / 256, 256, 0, stream>>>(x_flow, fA, n);
        n = N_HOST * DIM;
        cast_f32_bf16_k<<<(n / 4 + 255) / 256, 256, 0, stream>>>(x_host, hA, n);
        repack_w_k<<<dim3(8, NLAYER * 2), 256, 0, stream>>>(Wl, WlF);
        repack_w_k<<<dim3(8, NLAYER * 2), 256, 0, stream>>>(Wr, WrF);
        repack_wout_k<<<2, 256, 0, stream>>>(W_out, WoF);
    }

    // bucket partition (count -> scan -> scatter); no per-dst sort needed
    auto build_buckets = [&](const int* src, const int* dst, int nb,
                             int* bcount, int* boffs, int* bcur, int* bkey) {
        hipMemsetAsync(bcount, 0, (size_t)nb * 4, stream);
        bucket_count_k<<<(NEDGE + 8191) / 8192, 256, 0, stream>>>(dst, bcount, NEDGE, nb);
        bucket_scan_k<<<1, 256, 0, stream>>>(bcount, boffs, bcur, nb);
        bucket_scatter_k<<<(NEDGE + 255) / 256, 256, 0, stream>>>(src, dst, bcur, bkey, NEDGE);
    };
    build_buckets(ehf_src, ehf_dst, NB_F, bcountF, boffsF, bcurF, bkeyF);
    build_buckets(efh_src, efh_dst, NB_H, bcountH, boffsH, bcurH, bkeyH);

    // ---- layer 0 ----
    fused_sage_dual<<<NB_F, 256, 0, stream>>>(
        boffsF, bkeyF, (const bf16x8*)hA, fA,
        WlF + 0 * DIM * DIM, WrF + 0 * DIM * DIM,
        bl + 0 * DIM, br + 0 * DIM, fB, N_FLOW);
    fused_sage_dual<<<NB_H, 256, 0, stream>>>(
        boffsH, bkeyH, (const bf16x8*)fA, hA,
        WlF + 1 * DIM * DIM, WrF + 1 * DIM * DIM,
        bl + 1 * DIM, br + 1 * DIM, hB, N_HOST);

    // ---- layer 1 (host update dead; flow update fused with final projection) ----
    fused_sage_dual_out<<<NB_F, 256, 0, stream>>>(
        boffsF, bkeyF, (const bf16x8*)hB, fB,
        WlF + 2 * DIM * DIM, WrF + 2 * DIM * DIM,
        bl + 2 * DIM, br + 2 * DIM, WoF, b_out, out);
}

// Round 6
// 621.387 us; speedup vs baseline: 4.2278x; 4.2278x over previous
//
#include <hip/hip_runtime.h>
#include <stdint.h>

#define N_HOST 50000
#define N_FLOW 200000
#define DIM 128
#define DOUTN 32
#define NEDGE 1000000
#define NLAYER 2

#define GSH_F 8                      // flow: 256 dsts/bucket
#define GSH_H 6                      // host: 64 dsts/bucket
#define NB_F ((N_FLOW + (1 << GSH_F) - 1) >> GSH_F)   // 782
#define NB_H ((N_HOST + (1 << GSH_H) - 1) >> GSH_H)   // 782
#define AST 136                      // bf16 LDS row stride

typedef __bf16 bf16;
typedef __bf16 bf16x4 __attribute__((ext_vector_type(4)));
typedef __bf16 bf16x8 __attribute__((ext_vector_type(8)));
typedef float floatx4 __attribute__((ext_vector_type(4)));

// ---------------- cast f32 -> bf16 ----------------
__global__ void cast_f32_bf16_k(const float* __restrict__ in, bf16* __restrict__ out, int n) {
    int i = (blockIdx.x * 256 + threadIdx.x) * 4;
    if (i + 3 < n) {
        float4 v = *(const float4*)(in + i);
        bf16x4 o;
        o[0] = (bf16)v.x; o[1] = (bf16)v.y; o[2] = (bf16)v.z; o[3] = (bf16)v.w;
        *(bf16x4*)(out + i) = o;
    } else {
        for (int j = 0; j < 4 && i + j < n; ++j) out[i + j] = (bf16)in[i + j];
    }
}

// ---------------- weight repacks -> MFMA B-fragment layout ----------------
__global__ void repack_w_k(const float* __restrict__ W, bf16* __restrict__ out) {
    int mat = blockIdx.y;
    int w = blockIdx.x * 4 + (threadIdx.x >> 6);
    int lane = threadIdx.x & 63;
    int ct = w >> 2, k0q = w & 3;
    int quad = lane >> 4, m = lane & 15;
    const float* Wm = W + (size_t)mat * DIM * DIM;
    bf16* om = out + (size_t)mat * DIM * DIM;
    bf16x8 o;
#pragma unroll
    for (int j = 0; j < 8; ++j) o[j] = (bf16)Wm[(k0q * 32 + quad * 8 + j) * DIM + ct * 16 + m];
    *(bf16x8*)(om + ((ct * 4 + k0q) * 64 + lane) * 8) = o;
}

__global__ void repack_wout_k(const float* __restrict__ W, bf16* __restrict__ out) {
    int w = blockIdx.x * 4 + (threadIdx.x >> 6);
    int lane = threadIdx.x & 63;
    int ct = w >> 2, k0q = w & 3;
    int quad = lane >> 4, m = lane & 15;
    bf16x8 o;
#pragma unroll
    for (int j = 0; j < 8; ++j) o[j] = (bf16)W[(k0q * 32 + quad * 8 + j) * DOUTN + ct * 16 + m];
    *(bf16x8*)(out + ((ct * 4 + k0q) * 64 + lane) * 8) = o;
}

// ---------------- bucketed CSR build (R3-proven) ----------------
__global__ __launch_bounds__(256)
void bucket_count_k(const int* __restrict__ dst, int* __restrict__ bcount,
                    int n, int gsh, int nb) {
    __shared__ int lc[1024];
    int t = threadIdx.x;
    for (int i = t; i < nb; i += 256) lc[i] = 0;
    __syncthreads();
    int base = blockIdx.x * 4096;
    int end = base + 4096; if (end > n) end = n;
    for (int i = base + t; i < end; i += 256)
        atomicAdd(&lc[dst[i] >> gsh], 1);
    __syncthreads();
    for (int i = t; i < nb; i += 256) {
        int v = lc[i];
        if (v) atomicAdd(&bcount[i], v);
    }
}

__global__ __launch_bounds__(256)
void bucket_scan_k(const int* __restrict__ bcount, int* __restrict__ boffs,
                   int* __restrict__ bcur, int nb) {
    __shared__ int sd[256];
    int t = threadIdx.x;
    int v[4]; int ts = 0;
#pragma unroll
    for (int j = 0; j < 4; ++j) { int i = t * 4 + j; v[j] = (i < nb) ? bcount[i] : 0; ts += v[j]; }
    int x = ts;
    sd[t] = x; __syncthreads();
    for (int o = 1; o < 256; o <<= 1) {
        int y = (t >= o) ? sd[t - o] : 0;
        __syncthreads();
        x += y; sd[t] = x; __syncthreads();
    }
    int run = x - ts;
#pragma unroll
    for (int j = 0; j < 4; ++j) {
        int i = t * 4 + j;
        if (i < nb) { boffs[i] = run; bcur[i << 4] = run; }
        run += v[j];
    }
    if (t == 255) boffs[nb] = x;
}

__global__ __launch_bounds__(256)
void bucket_scatter_k(const int* __restrict__ src, const int* __restrict__ dst,
                      int* bcur, int* __restrict__ bkey, int n, int gsh) {
    int e = blockIdx.x * 256 + threadIdx.x;
    if (e < n) {
        int d = dst[e];
        int b = d >> gsh;
        int p = atomicAdd(&bcur[b << 4], 1);
        bkey[p] = (src[e] << 8) | (d & ((1 << gsh) - 1));
    }
}

__global__ __launch_bounds__(256)
void bucket_sort_k(const int* __restrict__ boffs, const int* __restrict__ bkey,
                   int* __restrict__ rs, int* __restrict__ es, int gsh) {
    __shared__ int cnts[256];
    __shared__ int sd[256];
    __shared__ int ldsout[2048];
    int b = blockIdx.x, t = threadIdx.x;
    int G = 1 << gsh;
    int base = boffs[b];
    int cnt = boffs[b + 1] - base;
    if (cnt > 2048) cnt = 2048;   // memory-safety only (>21 sigma for random input)
    int keys[8]; int nk = 0;
    for (int i = t; i < cnt; i += 256) keys[nk++] = bkey[base + i];
    cnts[t] = 0;
    __syncthreads();
    for (int j = 0; j < nk; ++j) atomicAdd(&cnts[keys[j] & 255], 1);
    __syncthreads();
    int v = cnts[t];
    int x = v;
    sd[t] = x; __syncthreads();
    for (int o = 1; o < 256; o <<= 1) {
        int y = (t >= o) ? sd[t - o] : 0;
        __syncthreads();
        x += y; sd[t] = x; __syncthreads();
    }
    int ex = x - v;
    if (t < G) rs[(b << gsh) + t] = base + ex;
    cnts[t] = ex;
    __syncthreads();
    for (int j = 0; j < nk; ++j) {
        int k = keys[j];
        int p = atomicAdd(&cnts[k & 255], 1);
        ldsout[p] = k >> 8;
    }
    __syncthreads();
    for (int i = t; i < cnt; i += 256) es[base + i] = ldsout[i];
}

// ---------------- segment mean: one wave per dst row, 4 edges in flight ----------
__global__ void aggregate_mean_q(const int* __restrict__ rs, const int* __restrict__ csr,
                                 const bf16x8* __restrict__ x8, bf16x8* __restrict__ m8, int n) {
    int wave = (blockIdx.x << 2) + (threadIdx.x >> 6);
    if (wave >= n) return;
    int lane = threadIdx.x & 63;
    int q = lane >> 4, c8 = lane & 15;
    int s0 = rs[wave], s1 = rs[wave + 1];
    float acc[8] = {0.f, 0.f, 0.f, 0.f, 0.f, 0.f, 0.f, 0.f};
    for (int e = s0 + q; e < s1; e += 4) {
        int s = csr[e];
        bf16x8 v = x8[s * 16 + c8];
#pragma unroll
        for (int j = 0; j < 8; ++j) acc[j] += (float)v[j];
    }
#pragma unroll
    for (int j = 0; j < 8; ++j) {
        acc[j] += __shfl_xor(acc[j], 16, 64);
        acc[j] += __shfl_xor(acc[j], 32, 64);
    }
    if (q == 0) {
        int deg = s1 - s0;
        float inv = 1.0f / (float)(deg > 0 ? deg : 1);
        bf16x8 o;
#pragma unroll
        for (int j = 0; j < 8; ++j) o[j] = (bf16)(acc[j] * inv);
        m8[wave * 16 + c8] = o;
    }
}

// ---------------- combined dual-table segment mean (layers 0 & 1 in one pass) ----
__global__ void aggregate_mean2(const int* __restrict__ rs, const int* __restrict__ csr,
                                const bf16x8* __restrict__ xa, const bf16x8* __restrict__ xb,
                                bf16x8* __restrict__ ma, bf16x8* __restrict__ mb, int n) {
    int wave = (blockIdx.x << 2) + (threadIdx.x >> 6);
    if (wave >= n) return;
    int lane = threadIdx.x & 63;
    int q = lane >> 4, c8 = lane & 15;
    int s0 = rs[wave], s1 = rs[wave + 1];
    float accA[8] = {0.f, 0.f, 0.f, 0.f, 0.f, 0.f, 0.f, 0.f};
    float accB[8] = {0.f, 0.f, 0.f, 0.f, 0.f, 0.f, 0.f, 0.f};
    for (int e = s0 + q; e < s1; e += 4) {
        int s = csr[e];
        bf16x8 va = xa[s * 16 + c8];
        bf16x8 vb = xb[s * 16 + c8];
#pragma unroll
        for (int j = 0; j < 8; ++j) { accA[j] += (float)va[j]; accB[j] += (float)vb[j]; }
    }
#pragma unroll
    for (int j = 0; j < 8; ++j) {
        accA[j] += __shfl_xor(accA[j], 16, 64);
        accA[j] += __shfl_xor(accA[j], 32, 64);
        accB[j] += __shfl_xor(accB[j], 16, 64);
        accB[j] += __shfl_xor(accB[j], 32, 64);
    }
    if (q == 0) {
        int deg = s1 - s0;
        float inv = 1.0f / (float)(deg > 0 ? deg : 1);
        bf16x8 oa, ob;
#pragma unroll
        for (int j = 0; j < 8; ++j) { oa[j] = (bf16)(accA[j] * inv); ob[j] = (bf16)(accB[j] * inv); }
        ma[wave * 16 + c8] = oa;
        mb[wave * 16 + c8] = ob;
    }
}

// ---------------- fused dual GEMM + bias + leaky_relu (B in registers) ----------
__global__ __launch_bounds__(256)
void gemm_dual_lrelu2(const bf16* __restrict__ A1, const bf16* __restrict__ A2,
                      const bf16* __restrict__ W1f, const bf16* __restrict__ W2f,
                      const float* __restrict__ b1, const float* __restrict__ b2,
                      bf16* __restrict__ out, int M) {
    int lane = threadIdx.x & 63;
    int gw = blockIdx.x * 4 + (threadIdx.x >> 6);
    int cp = gw & 3;
    int strip = gw >> 2;
    int nstrips = gridDim.x;
    int quad = lane >> 4, m = lane & 15;
    bf16x8 B1[2][4], B2[2][4];
#pragma unroll
    for (int t = 0; t < 2; ++t) {
        int ct = cp * 2 + t;
#pragma unroll
        for (int k = 0; k < 4; ++k) {
            B1[t][k] = *(const bf16x8*)(W1f + ((ct * 4 + k) * 64 + lane) * 8);
            B2[t][k] = *(const bf16x8*)(W2f + ((ct * 4 + k) * 64 + lane) * 8);
        }
    }
    int c0 = (cp * 2) * 16 + m, c1 = (cp * 2 + 1) * 16 + m;
    float bias0 = b1[c0] + b2[c0];
    float bias1 = b1[c1] + b2[c1];
    int nrt = M >> 4;
    for (int rt = strip; rt < nrt; rt += nstrips) {
        int row0 = rt << 4;
        floatx4 acc0 = {0.f, 0.f, 0.f, 0.f}, acc1 = {0.f, 0.f, 0.f, 0.f};
        const bf16* a1p = A1 + (row0 + m) * DIM + quad * 8;
        const bf16* a2p = A2 + (row0 + m) * DIM + quad * 8;
#pragma unroll
        for (int k = 0; k < 4; ++k) {
            bf16x8 a = *(const bf16x8*)(a1p + k * 32);
            acc0 = __builtin_amdgcn_mfma_f32_16x16x32_bf16(a, B1[0][k], acc0, 0, 0, 0);
            acc1 = __builtin_amdgcn_mfma_f32_16x16x32_bf16(a, B1[1][k], acc1, 0, 0, 0);
        }
#pragma unroll
        for (int k = 0; k < 4; ++k) {
            bf16x8 a = *(const bf16x8*)(a2p + k * 32);
            acc0 = __builtin_amdgcn_mfma_f32_16x16x32_bf16(a, B2[0][k], acc0, 0, 0, 0);
            acc1 = __builtin_amdgcn_mfma_f32_16x16x32_bf16(a, B2[1][k], acc1, 0, 0, 0);
        }
#pragma unroll
        for (int r = 0; r < 4; ++r) {
            int row = row0 + quad * 4 + r;
            float v0 = acc0[r] + bias0; v0 = v0 > 0.f ? v0 : 0.01f * v0;
            float v1 = acc1[r] + bias1; v1 = v1 > 0.f ? v1 : 0.01f * v1;
            out[row * DIM + c0] = (bf16)v0;
            out[row * DIM + c1] = (bf16)v1;
        }
    }
}

// ---------------- layer-1 flow GEMM + fused @W_out (f2 stays in LDS) ----------
// block = 64 rows (N_FLOW/64 = 3125 blocks exactly); wave wv = col pair wv.
__global__ __launch_bounds__(256)
void gemm_dual_out(const bf16* __restrict__ A1, const bf16* __restrict__ A2,
                   const bf16* __restrict__ W1f, const bf16* __restrict__ W2f,
                   const float* __restrict__ b1, const float* __restrict__ b2,
                   const bf16* __restrict__ Wof, const float* __restrict__ bo,
                   float* __restrict__ outf) {
    __shared__ __align__(16) bf16 f2[64 * AST];
    int t = threadIdx.x;
    int lane = t & 63, wv = t >> 6;
    int quad = lane >> 4, m = lane & 15;
    int row0 = blockIdx.x << 6;
    bf16x8 B1[2][4], B2[2][4];
#pragma unroll
    for (int tt = 0; tt < 2; ++tt) {
        int ct = wv * 2 + tt;
#pragma unroll
        for (int k = 0; k < 4; ++k) {
            B1[tt][k] = *(const bf16x8*)(W1f + ((ct * 4 + k) * 64 + lane) * 8);
            B2[tt][k] = *(const bf16x8*)(W2f + ((ct * 4 + k) * 64 + lane) * 8);
        }
    }
    int c0 = wv * 32 + m, c1 = wv * 32 + 16 + m;
    float bias0 = b1[c0] + b2[c0], bias1 = b1[c1] + b2[c1];
#pragma unroll
    for (int tm = 0; tm < 4; ++tm) {
        floatx4 a0 = {0.f, 0.f, 0.f, 0.f}, a1 = {0.f, 0.f, 0.f, 0.f};
        const bf16* a1p = A1 + (row0 + tm * 16 + m) * DIM + quad * 8;
        const bf16* a2p = A2 + (row0 + tm * 16 + m) * DIM + quad * 8;
#pragma unroll
        for (int k = 0; k < 4; ++k) {
            bf16x8 a = *(const bf16x8*)(a1p + k * 32);
            a0 = __builtin_amdgcn_mfma_f32_16x16x32_bf16(a, B1[0][k], a0, 0, 0, 0);
            a1 = __builtin_amdgcn_mfma_f32_16x16x32_bf16(a, B1[1][k], a1, 0, 0, 0);
        }
#pragma unroll
        for (int k = 0; k < 4; ++k) {
            bf16x8 a = *(const bf16x8*)(a2p + k * 32);
            a0 = __builtin_amdgcn_mfma_f32_16x16x32_bf16(a, B2[0][k], a0, 0, 0, 0);
            a1 = __builtin_amdgcn_mfma_f32_16x16x32_bf16(a, B2[1][k], a1, 0, 0, 0);
        }
#pragma unroll
        for (int r = 0; r < 4; ++r) {
            int lr = tm * 16 + quad * 4 + r;
            float v0 = a0[r] + bias0; v0 = v0 > 0.f ? v0 : 0.01f * v0;
            float v1 = a1[r] + bias1; v1 = v1 > 0.f ? v1 : 0.01f * v1;
            f2[lr * AST + c0] = (bf16)v0;
            f2[lr * AST + c1] = (bf16)v1;
        }
    }
    __syncthreads();
    // W_out stage: wave wv handles row-subtile wv (16 rows) x all 32 out-cols
    bf16x8 BO[2][4];
#pragma unroll
    for (int ct = 0; ct < 2; ++ct)
#pragma unroll
        for (int k = 0; k < 4; ++k)
            BO[ct][k] = *(const bf16x8*)(Wof + ((ct * 4 + k) * 64 + lane) * 8);
    floatx4 o0 = {0.f, 0.f, 0.f, 0.f}, o1 = {0.f, 0.f, 0.f, 0.f};
    const bf16* fp = f2 + (wv * 16 + m) * AST + quad * 8;
#pragma unroll
    for (int k = 0; k < 4; ++k) {
        bf16x8 af = *(const bf16x8*)(fp + k * 32);
        o0 = __builtin_amdgcn_mfma_f32_16x16x32_bf16(af, BO[0][k], o0, 0, 0, 0);
        o1 = __builtin_amdgcn_mfma_f32_16x16x32_bf16(af, BO[1][k], o1, 0, 0, 0);
    }
    float bo0 = bo[m], bo1 = bo[16 + m];
#pragma unroll
    for (int r = 0; r < 4; ++r) {
        int row = row0 + wv * 16 + quad * 4 + r;
        outf[row * DOUTN + m] = o0[r] + bo0;
        outf[row * DOUTN + 16 + m] = o1[r] + bo1;
    }
}

extern "C" void kernel_launch(void* const* d_in, const int* in_sizes, int n_in,
                              void* d_out, int out_size, void* d_ws, size_t ws_size,
                              hipStream_t stream) {
    (void)in_sizes; (void)n_in; (void)out_size; (void)ws_size;
    const float* x_host  = (const float*)d_in[0];
    const float* x_flow  = (const float*)d_in[1];
    const int*   ehf_src = (const int*)d_in[2];
    const int*   ehf_dst = (const int*)d_in[3];
    const int*   efh_src = (const int*)d_in[4];
    const int*   efh_dst = (const int*)d_in[5];
    const float* Wl      = (const float*)d_in[6];
    const float* bl      = (const float*)d_in[7];
    const float* Wr      = (const float*)d_in[8];
    const float* br      = (const float*)d_in[9];
    const float* W_out   = (const float*)d_in[10];
    const float* b_out   = (const float*)d_in[11];
    float* out = (float*)d_out;

    char* basep = (char*)d_ws;
    size_t off = 0;
    auto alloc = [&](size_t b) -> void* {
        void* p = basep + off;
        off += (b + 255) & ~(size_t)255;
        return p;
    };

    bf16* fA     = (bf16*)alloc((size_t)N_FLOW * DIM * 2);
    bf16* fB     = (bf16*)alloc((size_t)N_FLOW * DIM * 2);
    bf16* hA     = (bf16*)alloc((size_t)N_HOST * DIM * 2);
    bf16* hB     = (bf16*)alloc((size_t)N_HOST * DIM * 2);
    bf16* meanH  = (bf16*)alloc((size_t)N_HOST * DIM * 2);
    bf16* meanF0 = (bf16*)alloc((size_t)N_FLOW * DIM * 2);
    bf16* meanF1 = (bf16*)alloc((size_t)N_FLOW * DIM * 2);
    bf16* WlF    = (bf16*)alloc((size_t)NLAYER * 2 * DIM * DIM * 2);
    bf16* WrF    = (bf16*)alloc((size_t)NLAYER * 2 * DIM * DIM * 2);
    bf16* WoF    = (bf16*)alloc((size_t)DIM * DOUTN * 2);

    int* bcountF = (int*)alloc((size_t)NB_F * 4);
    int* boffsF  = (int*)alloc((size_t)(NB_F + 1) * 4);
    int* bcurF   = (int*)alloc((size_t)NB_F * 16 * 4);
    int* bkeyF   = (int*)alloc((size_t)NEDGE * 4);
    int* rsF     = (int*)alloc((size_t)(NB_F * (1 << GSH_F) + 1) * 4);
    int* esF     = (int*)alloc((size_t)NEDGE * 4);
    int* bcountH = (int*)alloc((size_t)NB_H * 4);
    int* boffsH  = (int*)alloc((size_t)(NB_H + 1) * 4);
    int* bcurH   = (int*)alloc((size_t)NB_H * 16 * 4);
    int* bkeyH   = (int*)alloc((size_t)NEDGE * 4);
    int* rsH     = (int*)alloc((size_t)(NB_H * (1 << GSH_H) + 1) * 4);
    int* esH     = (int*)alloc((size_t)NEDGE * 4);

    // casts + weight repacks
    {
        int n = N_FLOW * DIM;
        cast_f32_bf16_k<<<(n / 4 + 255) / 256, 256, 0, stream>>>(x_flow, fA, n);
        n = N_HOST * DIM;
        cast_f32_bf16_k<<<(n / 4 + 255) / 256, 256, 0, stream>>>(x_host, hA, n);
        repack_w_k<<<dim3(8, NLAYER * 2), 256, 0, stream>>>(Wl, WlF);
        repack_w_k<<<dim3(8, NLAYER * 2), 256, 0, stream>>>(Wr, WrF);
        repack_wout_k<<<2, 256, 0, stream>>>(W_out, WoF);
    }

    // bucketed CSR build (both directions)
    auto build_csr = [&](const int* src, const int* dst, int gsh, int nb,
                         int* bcount, int* boffs, int* bcur, int* bkey, int* rs, int* es) {
        hipMemsetAsync(bcount, 0, (size_t)nb * 4, stream);
        bucket_count_k<<<(NEDGE + 4095) / 4096, 256, 0, stream>>>(dst, bcount, NEDGE, gsh, nb);
        bucket_scan_k<<<1, 256, 0, stream>>>(bcount, boffs, bcur, nb);
        bucket_scatter_k<<<(NEDGE + 255) / 256, 256, 0, stream>>>(src, dst, bcur, bkey, NEDGE, gsh);
        bucket_sort_k<<<nb, 256, 0, stream>>>(boffs, bkey, rs, es, gsh);
    };
    build_csr(ehf_src, ehf_dst, GSH_F, NB_F, bcountF, boffsF, bcurF, bkeyF, rsF, esF);
    build_csr(efh_src, efh_dst, GSH_H, NB_H, bcountH, boffsH, bcurH, bkeyH, rsH, esH);

    // ---- host update (layer 0 only; layer-1 host update is dead) ----
    aggregate_mean_q<<<(N_HOST + 3) / 4, 256, 0, stream>>>(
        rsH, esH, (const bf16x8*)fA, (bf16x8*)meanH, N_HOST);
    gemm_dual_lrelu2<<<512, 256, 0, stream>>>(
        meanH, hA, WlF + 1 * DIM * DIM, WrF + 1 * DIM * DIM,
        bl + 1 * DIM, br + 1 * DIM, hB, N_HOST);

    // ---- both flow gathers in one pass (h0 and h1 tables) ----
    aggregate_mean2<<<(N_FLOW + 3) / 4, 256, 0, stream>>>(
        rsF, esF, (const bf16x8*)hA, (const bf16x8*)hB,
        (bf16x8*)meanF0, (bf16x8*)meanF1, N_FLOW);

    // ---- layer-0 flow update ----
    gemm_dual_lrelu2<<<1024, 256, 0, stream>>>(
        meanF0, fA, WlF + 0 * DIM * DIM, WrF + 0 * DIM * DIM,
        bl + 0 * DIM, br + 0 * DIM, fB, N_FLOW);

    // ---- layer-1 flow update fused with final projection ----
    gemm_dual_out<<<N_FLOW / 64, 256, 0, stream>>>(
        meanF1, fB, WlF + 2 * DIM * DIM, WrF + 2 * DIM * DIM,
        bl + 2 * DIM, br + 2 * DIM, WoF, b_out, out);
}